// Round 9
// baseline (379.170 us; speedup 1.0000x reference)
//
#include <hip/hip_runtime.h>
#include <stdint.h>
#include <math.h>

#define T_SEQ 4096
#define DM 1024
#define NH 16
#define DH 64
#define QSCALE 0.1803368801111137f  // 0.125 * log2(e): softmax done in exp2 domain

typedef unsigned short u16;
typedef __attribute__((ext_vector_type(8))) short bfx8;    // 8 bf16 = 4 VGPR
typedef __attribute__((ext_vector_type(4))) float f4;      // 16x16 MFMA C/D
typedef __attribute__((ext_vector_type(16))) float f16f;   // 32x32 MFMA C/D
typedef __attribute__((ext_vector_type(4))) uint32_t u32x4;

__device__ inline u16 f2bf(float f) {
  uint32_t u = __float_as_uint(f);
  u = (u + 0x7fffu + ((u >> 16) & 1u)) >> 16;
  return (u16)u;
}

__device__ inline uint32_t cvtpk(float lo, float hi) {
  uint32_t r;
  asm("v_cvt_pk_bf16_f32 %0, %1, %2" : "=v"(r) : "v"(lo), "v"(hi));
  return r;
}
// swaps: vdst lanes 32-63 <-> vsrc lanes 0-31 (both modified)
__device__ inline void pl32(uint32_t &a, uint32_t &b) {
  asm volatile("v_permlane32_swap_b32 %0, %1" : "+v"(a), "+v"(b));
}

// async global->LDS, 16B per lane. LDS dest must be uniform-base + lane*16.
__device__ inline void gl_lds16(const void* g, void* l) {
  __builtin_amdgcn_global_load_lds(
      (__attribute__((address_space(1))) uint32_t*)const_cast<void*>(g),
      (__attribute__((address_space(3))) uint32_t*)l, 16, 0, 0);
}

// ---------------- fp32 -> bf16 converts ----------------
__global__ __launch_bounds__(256) void cvt_kernel(const float* __restrict__ src,
                                                  u16* __restrict__ dst, int n8) {
  int i = blockIdx.x * 256 + threadIdx.x;
  if (i >= n8) return;
  const float4* s = (const float4*)src + (size_t)i * 2;
  float4 a = s[0], b = s[1];
  union { u16 u[8]; bfx8 v; } o;
  o.u[0] = f2bf(a.x); o.u[1] = f2bf(a.y); o.u[2] = f2bf(a.z); o.u[3] = f2bf(a.w);
  o.u[4] = f2bf(b.x); o.u[5] = f2bf(b.y); o.u[6] = f2bf(b.z); o.u[7] = f2bf(b.w);
  *(bfx8*)(dst + (size_t)i * 8) = o.v;
}

__global__ __launch_bounds__(256) void cvt4_kernel(
    const float* __restrict__ a, const float* __restrict__ b,
    const float* __restrict__ c, const float* __restrict__ d,
    u16* __restrict__ oa, u16* __restrict__ ob, u16* __restrict__ oc, u16* __restrict__ od) {
  int z = blockIdx.y;
  const float* s = (z == 0) ? a : (z == 1) ? b : (z == 2) ? c : d;
  u16* o = (z == 0) ? oa : (z == 1) ? ob : (z == 2) ? oc : od;
  int i = blockIdx.x * 256 + threadIdx.x;
  const float4* sp = (const float4*)s + (size_t)i * 2;
  float4 x = sp[0], y = sp[1];
  union { u16 u[8]; bfx8 v; } t;
  t.u[0] = f2bf(x.x); t.u[1] = f2bf(x.y); t.u[2] = f2bf(x.z); t.u[3] = f2bf(x.w);
  t.u[4] = f2bf(y.x); t.u[5] = f2bf(y.y); t.u[6] = f2bf(y.z); t.u[7] = f2bf(y.w);
  *(bfx8*)(o + (size_t)i * 8) = t.v;
}

// ---------------- QKV projection GEMM (NT): y = x @ W^T + b ----------------
__global__ __launch_bounds__(256) void gemm_qkv(
    const u16* __restrict__ xb,
    const u16* __restrict__ wq, const u16* __restrict__ wk, const u16* __restrict__ wv,
    const float* __restrict__ bq, const float* __restrict__ bk, const float* __restrict__ bv,
    u16* __restrict__ qo, u16* __restrict__ ko, u16* __restrict__ vo) {
  __shared__ u16 sA[128 * 32];
  __shared__ u16 sB[128 * 32];
  const int mode = blockIdx.z;
  const u16* w = (mode == 0) ? wq : (mode == 1) ? wk : wv;
  const float* bias = (mode == 0) ? bq : (mode == 1) ? bk : bv;
  const int tid = threadIdx.x, lane = tid & 63, wid = tid >> 6;
  const int wr = wid >> 1, wc = wid & 1;
  const int row0 = blockIdx.y * 128, col0 = blockIdx.x * 128;
  f4 acc[4][4] = {};

  for (int kt = 0; kt < DM / 32; ++kt) {
#pragma unroll
    for (int i = 0; i < 2; ++i) {
      int c = i * 4 + wid;
      int r = c * 16 + (lane >> 2);
      int s = (lane & 3) ^ ((r >> 1) & 3);
      gl_lds16(xb + (size_t)(row0 + r) * DM + kt * 32 + s * 8, &sA[c * 512 + lane * 8]);
      gl_lds16(w  + (size_t)(col0 + r) * DM + kt * 32 + s * 8, &sB[c * 512 + lane * 8]);
    }
    __syncthreads();
    bfx8 a[4], b[4];
#pragma unroll
    for (int t = 0; t < 4; ++t) {
      int ra = wr * 64 + t * 16 + (lane & 15);
      a[t] = *(const bfx8*)&sA[ra * 32 + (((lane >> 4) ^ ((ra >> 1) & 3)) * 8)];
      int rb = wc * 64 + t * 16 + (lane & 15);
      b[t] = *(const bfx8*)&sB[rb * 32 + (((lane >> 4) ^ ((rb >> 1) & 3)) * 8)];
    }
#pragma unroll
    for (int mt = 0; mt < 4; ++mt)
#pragma unroll
      for (int nt = 0; nt < 4; ++nt)
        acc[mt][nt] = __builtin_amdgcn_mfma_f32_16x16x32_bf16(a[mt], b[nt], acc[mt][nt], 0, 0, 0);
    __syncthreads();
  }

#pragma unroll
  for (int mt = 0; mt < 4; ++mt) {
#pragma unroll
    for (int nt = 0; nt < 4; ++nt) {
      int n = col0 + wc * 64 + nt * 16 + (lane & 15);
      float bv_ = bias[n];
      int h = n >> 6, d = n & 63;
#pragma unroll
      for (int r = 0; r < 4; ++r) {
        int mrow = row0 + wr * 64 + mt * 16 + (lane >> 4) * 4 + r;
        float v = acc[mt][nt][r] + bv_;
        if (mode == 0)      qo[(size_t)h * (T_SEQ * DH) + (size_t)mrow * DH + d] = f2bf(v * QSCALE);
        else if (mode == 1) ko[(size_t)h * (T_SEQ * DH) + (size_t)mrow * DH + d] = f2bf(v);
        else                vo[(size_t)h * (DH * T_SEQ) + (size_t)d * T_SEQ + mrow] = f2bf(v);
      }
    }
  }
}

// ---------------- output projection GEMM: out = ao @ Wo^T + bo (fp32 out) ----------------
__global__ __launch_bounds__(256) void gemm_out(
    const u16* __restrict__ ab, const u16* __restrict__ wo,
    const float* __restrict__ bo, float* __restrict__ out) {
  __shared__ u16 sA[128 * 32];
  __shared__ u16 sB[128 * 32];
  const int tid = threadIdx.x, lane = tid & 63, wid = tid >> 6;
  const int wr = wid >> 1, wc = wid & 1;
  const int row0 = blockIdx.y * 128, col0 = blockIdx.x * 128;
  f4 acc[4][4] = {};

  for (int kt = 0; kt < DM / 32; ++kt) {
#pragma unroll
    for (int i = 0; i < 2; ++i) {
      int c = i * 4 + wid;
      int r = c * 16 + (lane >> 2);
      int s = (lane & 3) ^ ((r >> 1) & 3);
      gl_lds16(ab + (size_t)(row0 + r) * DM + kt * 32 + s * 8, &sA[c * 512 + lane * 8]);
      gl_lds16(wo + (size_t)(col0 + r) * DM + kt * 32 + s * 8, &sB[c * 512 + lane * 8]);
    }
    __syncthreads();
    bfx8 a[4], b[4];
#pragma unroll
    for (int t = 0; t < 4; ++t) {
      int ra = wr * 64 + t * 16 + (lane & 15);
      a[t] = *(const bfx8*)&sA[ra * 32 + (((lane >> 4) ^ ((ra >> 1) & 3)) * 8)];
      int rb = wc * 64 + t * 16 + (lane & 15);
      b[t] = *(const bfx8*)&sB[rb * 32 + (((lane >> 4) ^ ((rb >> 1) & 3)) * 8)];
    }
#pragma unroll
    for (int mt = 0; mt < 4; ++mt)
#pragma unroll
      for (int nt = 0; nt < 4; ++nt)
        acc[mt][nt] = __builtin_amdgcn_mfma_f32_16x16x32_bf16(a[mt], b[nt], acc[mt][nt], 0, 0, 0);
    __syncthreads();
  }

#pragma unroll
  for (int mt = 0; mt < 4; ++mt) {
#pragma unroll
    for (int nt = 0; nt < 4; ++nt) {
      int n = col0 + wc * 64 + nt * 16 + (lane & 15);
      float bv_ = bo[n];
#pragma unroll
      for (int r = 0; r < 4; ++r) {
        int mrow = row0 + wr * 64 + mt * 16 + (lane >> 4) * 4 + r;
        out[(size_t)mrow * DM + n] = acc[mt][nt][r] + bv_;
      }
    }
  }
}

// ---------------- flash attention: LDS-free, reg-resident K/V from L2 ----------------
// 4 waves x QBLK=32 per block, grid 512 (2 blocks/CU, same head per CU -> L1 reuse).
// S^T = mfma(K, Q); O^T = mfma(V^T, P^T); per-lane online softmax; no barriers at all.
// K double-buffered in regs (unroll-2 named buffers); V issued at phase top, used post-softmax.

#define MFMA32(A, B, C) __builtin_amdgcn_mfma_f32_32x32x16_bf16(A, B, C, 0, 0, 0)

__device__ __forceinline__ void softmax_pack(
    f16f& s0, f16f& s1, float& m, float& l, f16f& o0, f16f& o1,
    bfx8& pa0, bfx8& pa1, bfx8& pa2, bfx8& pa3) {
  // tree max over the 32 per-lane scores
  float u[8];
#pragma unroll
  for (int r = 0; r < 8; ++r) u[r] = fmaxf(s0[r], s0[r + 8]);
#pragma unroll
  for (int r = 0; r < 8; ++r) u[r] = fmaxf(u[r], fmaxf(s1[r], s1[r + 8]));
  float tm = fmaxf(fmaxf(fmaxf(u[0], u[1]), fmaxf(u[2], u[3])),
                   fmaxf(fmaxf(u[4], u[5]), fmaxf(u[6], u[7])));
  tm = fmaxf(tm, __shfl_xor(tm, 32));
  // T13 defer-max: only rescale when some lane's tile-max exceeds m+8 (exp2 domain)
  if (!__all(tm <= m + 8.0f)) {
    float mn = fmaxf(m, tm);
    float fsc = __builtin_amdgcn_exp2f(m - mn);
    m = mn; l *= fsc;
#pragma unroll
    for (int r = 0; r < 16; ++r) { o0[r] *= fsc; o1[r] *= fsc; }
  }
#pragma unroll
  for (int r = 0; r < 16; ++r) s0[r] = __builtin_amdgcn_exp2f(s0[r] - m);
#pragma unroll
  for (int r = 0; r < 16; ++r) s1[r] = __builtin_amdgcn_exp2f(s1[r] - m);
  float q0 = 0.f, q1 = 0.f, q2 = 0.f, q3 = 0.f;
#pragma unroll
  for (int r = 0; r < 4; ++r) {
    q0 += s0[r]; q1 += s0[r + 4]; q2 += s0[r + 8]; q3 += s0[r + 12];
    q0 += s1[r]; q1 += s1[r + 4]; q2 += s1[r + 8]; q3 += s1[r + 12];
  }
  float ps = (q0 + q1) + (q2 + q3);
  ps += __shfl_xor(ps, 32);
  l += ps;
  // P(f32, S^T layout) -> bf16 PV fragments via cvt_pk + permlane32_swap (T12)
  uint32_t a0, a1, a2, a3;
#define PACK(SS, i0, PA)                                                     \
  a0 = cvtpk(SS[i0 + 0], SS[i0 + 1]); a1 = cvtpk(SS[i0 + 2], SS[i0 + 3]);    \
  a2 = cvtpk(SS[i0 + 4], SS[i0 + 5]); a3 = cvtpk(SS[i0 + 6], SS[i0 + 7]);    \
  pl32(a0, a2); pl32(a1, a3);                                                \
  { u32x4 t_; t_[0] = a0; t_[1] = a1; t_[2] = a2; t_[3] = a3;                \
    PA = __builtin_bit_cast(bfx8, t_); }
  PACK(s0, 0, pa0) PACK(s0, 8, pa1) PACK(s1, 0, pa2) PACK(s1, 8, pa3)
#undef PACK
}

__global__ __launch_bounds__(256, 2) void attn_kernel(
    const u16* __restrict__ qb, const u16* __restrict__ kb,
    const u16* __restrict__ vb, u16* __restrict__ ao) {
  const int tid = threadIdx.x, lane = tid & 63, wid = tid >> 6;  // wid 0..3
  const int hi = lane >> 5, q32 = lane & 31;
  const int bid = blockIdx.x;
  // XCD-aware: 2 heads per XCD (K/V 2MB fits the 4MB per-XCD L2); same head on both blocks of a CU
  const int h = (bid & 7) * 2 + ((bid >> 3) & 1);
  const int qr0 = (bid >> 4) * 128 + wid * 32;
  const size_t hoff = (size_t)h * ((size_t)T_SEQ * DH);

  // Q fragments (B-operand): Q[q=lane&31][d = 16*ds + 8*hi + j]
  bfx8 qf0, qf1, qf2, qf3;
  {
    const u16* qp = qb + hoff + (size_t)(qr0 + q32) * DH + hi * 8;
    qf0 = *(const bfx8*)(qp);
    qf1 = *(const bfx8*)(qp + 16);
    qf2 = *(const bfx8*)(qp + 32);
    qf3 = *(const bfx8*)(qp + 48);
  }

  f16f o0 = {}, o1 = {};          // O^T accum: d rows 0-31 / 32-63, col q=lane&31
  float m = -INFINITY, l = 0.f;

  // per-lane fragment base pointers (include hi*8 slot base)
  const u16* kp0 = kb + hoff + (size_t)q32 * DH + hi * 8;          // K row q32
  const u16* kp1 = kp0 + 32 * DH;                                   // K row q32+32
  const u16* vp0 = vb + hoff + (size_t)q32 * T_SEQ + hi * 8;        // V^T row q32
  const u16* vp1 = vp0 + (size_t)32 * T_SEQ;                        // V^T row q32+32

  // K double buffer (A/B), 8 frags each
  bfx8 Aa0, Aa1, Aa2, Aa3, Ab0, Ab1, Ab2, Ab3;
  bfx8 Ba0 = {}, Ba1 = {}, Ba2 = {}, Ba3 = {}, Bb0 = {}, Bb1 = {}, Bb2 = {}, Bb3 = {};

  // prologue: K tile 0 -> A
  Aa0 = *(const bfx8*)(kp0);      Aa1 = *(const bfx8*)(kp0 + 16);
  Aa2 = *(const bfx8*)(kp0 + 32); Aa3 = *(const bfx8*)(kp0 + 48);
  Ab0 = *(const bfx8*)(kp1);      Ab1 = *(const bfx8*)(kp1 + 16);
  Ab2 = *(const bfx8*)(kp1 + 32); Ab3 = *(const bfx8*)(kp1 + 48);
  kp0 += 64 * DH; kp1 += 64 * DH;

  const int NT = T_SEQ / 64;

#define PHASE(KC, KN, PREF)                                                    \
  {                                                                            \
    /* V loads for this tile (consumed after softmax, ~300cy later) */         \
    bfx8 w0 = *(const bfx8*)(vp0);       bfx8 w1 = *(const bfx8*)(vp0 + 16);   \
    bfx8 w2 = *(const bfx8*)(vp0 + 32);  bfx8 w3 = *(const bfx8*)(vp0 + 48);   \
    bfx8 y0 = *(const bfx8*)(vp1);       bfx8 y1 = *(const bfx8*)(vp1 + 16);   \
    bfx8 y2 = *(const bfx8*)(vp1 + 32);  bfx8 y3 = *(const bfx8*)(vp1 + 48);   \
    vp0 += 64; vp1 += 64;                                                      \
    if (PREF) { /* prefetch next K tile into the other buffer */               \
      KN##a0 = *(const bfx8*)(kp0);      KN##a1 = *(const bfx8*)(kp0 + 16);    \
      KN##a2 = *(const bfx8*)(kp0 + 32); KN##a3 = *(const bfx8*)(kp0 + 48);    \
      KN##b0 = *(const bfx8*)(kp1);      KN##b1 = *(const bfx8*)(kp1 + 16);    \
      KN##b2 = *(const bfx8*)(kp1 + 32); KN##b3 = *(const bfx8*)(kp1 + 48);    \
      kp0 += 64 * DH; kp1 += 64 * DH;                                          \
    }                                                                          \
    f16f s0 = {}, s1 = {};                                                     \
    __builtin_amdgcn_s_setprio(1);                                             \
    s0 = MFMA32(KC##a0, qf0, s0); s1 = MFMA32(KC##b0, qf0, s1);                \
    s0 = MFMA32(KC##a1, qf1, s0); s1 = MFMA32(KC##b1, qf1, s1);                \
    s0 = MFMA32(KC##a2, qf2, s0); s1 = MFMA32(KC##b2, qf2, s1);                \
    s0 = MFMA32(KC##a3, qf3, s0); s1 = MFMA32(KC##b3, qf3, s1);                \
    __builtin_amdgcn_s_setprio(0);                                             \
    bfx8 pa0, pa1, pa2, pa3;                                                   \
    softmax_pack(s0, s1, m, l, o0, o1, pa0, pa1, pa2, pa3);                    \
    __builtin_amdgcn_s_setprio(1);                                             \
    o0 = MFMA32(w0, pa0, o0); o1 = MFMA32(y0, pa0, o1);                        \
    o0 = MFMA32(w1, pa1, o0); o1 = MFMA32(y1, pa1, o1);                        \
    o0 = MFMA32(w2, pa2, o0); o1 = MFMA32(y2, pa2, o1);                        \
    o0 = MFMA32(w3, pa3, o0); o1 = MFMA32(y3, pa3, o1);                        \
    __builtin_amdgcn_s_setprio(0);                                             \
  }

  for (int kt = 0; kt < NT; kt += 2) {
    PHASE(A, B, true)
    PHASE(B, A, (kt + 2 < NT))
  }
#undef PHASE

  // epilogue: O^T[d][q] -> ao[t][h*64+d], normalize by l
  float inv = 1.0f / l;
  u16* orow = ao + (size_t)(qr0 + q32) * DM + h * DH;
#pragma unroll
  for (int r = 0; r < 16; ++r) {
    int d0 = (r & 3) + 8 * (r >> 2) + 4 * hi;
    orow[d0]      = f2bf(o0[r] * inv);
    orow[32 + d0] = f2bf(o1[r] * inv);
  }
}

extern "C" void kernel_launch(void* const* d_in, const int* in_sizes, int n_in,
                              void* d_out, int out_size, void* d_ws, size_t ws_size,
                              hipStream_t stream) {
  const float* x  = (const float*)d_in[0];
  const float* Wq = (const float*)d_in[1];
  const float* bq = (const float*)d_in[2];
  const float* Wk = (const float*)d_in[3];
  const float* bk = (const float*)d_in[4];
  const float* Wv = (const float*)d_in[5];
  const float* bv = (const float*)d_in[6];
  const float* Wo = (const float*)d_in[7];
  const float* bo = (const float*)d_in[8];
  float* out = (float*)d_out;

  u16* ws  = (u16*)d_ws;
  u16* xb  = ws;                                // [4096][1024]
  u16* wqb = xb + (size_t)T_SEQ * DM;           // [1024][1024] each
  u16* wkb = wqb + (size_t)DM * DM;
  u16* wvb = wkb + (size_t)DM * DM;
  u16* wob = wvb + (size_t)DM * DM;
  u16* qbb = wob + (size_t)DM * DM;             // [16][4096][64] (q, pre-scaled)
  u16* kbb = qbb + (size_t)T_SEQ * DM;          // [16][4096][64]
  u16* vbb = kbb + (size_t)T_SEQ * DM;          // [16][64][4096] (transposed)
  u16* abb = vbb + (size_t)T_SEQ * DM;          // [4096][1024] attn merged

  cvt_kernel<<<(T_SEQ * DM / 8) / 256, 256, 0, stream>>>(x, xb, T_SEQ * DM / 8);
  cvt4_kernel<<<dim3((DM * DM / 8) / 256, 4), 256, 0, stream>>>(
      Wq, Wk, Wv, Wo, wqb, wkb, wvb, wob);

  gemm_qkv<<<dim3(DM / 128, T_SEQ / 128, 3), 256, 0, stream>>>(
      xb, wqb, wkb, wvb, bq, bk, bv, qbb, kbb, vbb);

  attn_kernel<<<512, 256, 0, stream>>>(qbb, kbb, vbb, abb);

  gemm_out<<<dim3(DM / 128, T_SEQ / 128), 256, 0, stream>>>(abb, wob, bo, out);
}

// Round 11
// 246.575 us; speedup vs baseline: 1.5377x; 1.5377x over previous
//
#include <hip/hip_runtime.h>
#include <stdint.h>
#include <math.h>

#define T_SEQ 4096
#define DM 1024
#define NH 16
#define DH 64
#define QSCALE 0.1803368801111137f  // 0.125 * log2(e): softmax done in exp2 domain

typedef unsigned short u16;
typedef __attribute__((ext_vector_type(8))) short bfx8;    // 8 bf16 = 4 VGPR
typedef __attribute__((ext_vector_type(4))) float f4;      // 16x16 MFMA C/D
typedef __attribute__((ext_vector_type(16))) float f16f;   // 32x32 MFMA C/D
typedef __attribute__((ext_vector_type(4))) uint32_t u32x4;
typedef __attribute__((ext_vector_type(2))) float f2;

__device__ inline u16 f2bf(float f) {
  uint32_t u = __float_as_uint(f);
  u = (u + 0x7fffu + ((u >> 16) & 1u)) >> 16;
  return (u16)u;
}

__device__ inline uint32_t cvtpk(float lo, float hi) {
  uint32_t r;
  asm("v_cvt_pk_bf16_f32 %0, %1, %2" : "=v"(r) : "v"(lo), "v"(hi));
  return r;
}
// swaps: vdst lanes 32-63 <-> vsrc lanes 0-31 (both modified)
__device__ inline void pl32(uint32_t &a, uint32_t &b) {
  asm volatile("v_permlane32_swap_b32 %0, %1" : "+v"(a), "+v"(b));
}

// async global->LDS, 16B per lane. LDS dest must be uniform-base + lane*16.
__device__ inline void gl_lds16(const void* g, void* l) {
  __builtin_amdgcn_global_load_lds(
      (__attribute__((address_space(1))) uint32_t*)const_cast<void*>(g),
      (__attribute__((address_space(3))) uint32_t*)l, 16, 0, 0);
}

__device__ __forceinline__ f2 mkf2(float a, float b) { f2 r; r[0] = a; r[1] = b; return r; }
__device__ __forceinline__ f2 pkmax(f2 a, f2 b) {
  f2 r; r[0] = fmaxf(a[0], b[0]); r[1] = fmaxf(a[1], b[1]); return r;
}

// ---------------- fp32 -> bf16 converts ----------------
__global__ __launch_bounds__(256) void cvt_kernel(const float* __restrict__ src,
                                                  u16* __restrict__ dst, int n8) {
  int i = blockIdx.x * 256 + threadIdx.x;
  if (i >= n8) return;
  const float4* s = (const float4*)src + (size_t)i * 2;
  float4 a = s[0], b = s[1];
  union { u16 u[8]; bfx8 v; } o;
  o.u[0] = f2bf(a.x); o.u[1] = f2bf(a.y); o.u[2] = f2bf(a.z); o.u[3] = f2bf(a.w);
  o.u[4] = f2bf(b.x); o.u[5] = f2bf(b.y); o.u[6] = f2bf(b.z); o.u[7] = f2bf(b.w);
  *(bfx8*)(dst + (size_t)i * 8) = o.v;
}

__global__ __launch_bounds__(256) void cvt4_kernel(
    const float* __restrict__ a, const float* __restrict__ b,
    const float* __restrict__ c, const float* __restrict__ d,
    u16* __restrict__ oa, u16* __restrict__ ob, u16* __restrict__ oc, u16* __restrict__ od) {
  int z = blockIdx.y;
  const float* s = (z == 0) ? a : (z == 1) ? b : (z == 2) ? c : d;
  u16* o = (z == 0) ? oa : (z == 1) ? ob : (z == 2) ? oc : od;
  int i = blockIdx.x * 256 + threadIdx.x;
  const float4* sp = (const float4*)s + (size_t)i * 2;
  float4 x = sp[0], y = sp[1];
  union { u16 u[8]; bfx8 v; } t;
  t.u[0] = f2bf(x.x); t.u[1] = f2bf(x.y); t.u[2] = f2bf(x.z); t.u[3] = f2bf(x.w);
  t.u[4] = f2bf(y.x); t.u[5] = f2bf(y.y); t.u[6] = f2bf(y.z); t.u[7] = f2bf(y.w);
  *(bfx8*)(o + (size_t)i * 8) = t.v;
}

// ---------------- QKV projection GEMM (NT): y = x @ W^T + b ----------------
__global__ __launch_bounds__(256) void gemm_qkv(
    const u16* __restrict__ xb,
    const u16* __restrict__ wq, const u16* __restrict__ wk, const u16* __restrict__ wv,
    const float* __restrict__ bq, const float* __restrict__ bk, const float* __restrict__ bv,
    u16* __restrict__ qo, u16* __restrict__ ko, u16* __restrict__ vo) {
  __shared__ u16 sA[128 * 32];
  __shared__ u16 sB[128 * 32];
  const int mode = blockIdx.z;
  const u16* w = (mode == 0) ? wq : (mode == 1) ? wk : wv;
  const float* bias = (mode == 0) ? bq : (mode == 1) ? bk : bv;
  const int tid = threadIdx.x, lane = tid & 63, wid = tid >> 6;
  const int wr = wid >> 1, wc = wid & 1;
  const int row0 = blockIdx.y * 128, col0 = blockIdx.x * 128;
  f4 acc[4][4] = {};

  for (int kt = 0; kt < DM / 32; ++kt) {
#pragma unroll
    for (int i = 0; i < 2; ++i) {
      int c = i * 4 + wid;
      int r = c * 16 + (lane >> 2);
      int s = (lane & 3) ^ ((r >> 1) & 3);
      gl_lds16(xb + (size_t)(row0 + r) * DM + kt * 32 + s * 8, &sA[c * 512 + lane * 8]);
      gl_lds16(w  + (size_t)(col0 + r) * DM + kt * 32 + s * 8, &sB[c * 512 + lane * 8]);
    }
    __syncthreads();
    bfx8 a[4], b[4];
#pragma unroll
    for (int t = 0; t < 4; ++t) {
      int ra = wr * 64 + t * 16 + (lane & 15);
      a[t] = *(const bfx8*)&sA[ra * 32 + (((lane >> 4) ^ ((ra >> 1) & 3)) * 8)];
      int rb = wc * 64 + t * 16 + (lane & 15);
      b[t] = *(const bfx8*)&sB[rb * 32 + (((lane >> 4) ^ ((rb >> 1) & 3)) * 8)];
    }
#pragma unroll
    for (int mt = 0; mt < 4; ++mt)
#pragma unroll
      for (int nt = 0; nt < 4; ++nt)
        acc[mt][nt] = __builtin_amdgcn_mfma_f32_16x16x32_bf16(a[mt], b[nt], acc[mt][nt], 0, 0, 0);
    __syncthreads();
  }

#pragma unroll
  for (int mt = 0; mt < 4; ++mt) {
#pragma unroll
    for (int nt = 0; nt < 4; ++nt) {
      int n = col0 + wc * 64 + nt * 16 + (lane & 15);
      float bv_ = bias[n];
      int h = n >> 6, d = n & 63;
#pragma unroll
      for (int r = 0; r < 4; ++r) {
        int mrow = row0 + wr * 64 + mt * 16 + (lane >> 4) * 4 + r;
        float v = acc[mt][nt][r] + bv_;
        if (mode == 0)      qo[(size_t)h * (T_SEQ * DH) + (size_t)mrow * DH + d] = f2bf(v * QSCALE);
        else if (mode == 1) ko[(size_t)h * (T_SEQ * DH) + (size_t)mrow * DH + d] = f2bf(v);
        else                vo[(size_t)h * (DH * T_SEQ) + (size_t)d * T_SEQ + mrow] = f2bf(v);
      }
    }
  }
}

// ---------------- output projection GEMM: out = ao @ Wo^T + bo (fp32 out) ----------------
__global__ __launch_bounds__(256) void gemm_out(
    const u16* __restrict__ ab, const u16* __restrict__ wo,
    const float* __restrict__ bo, float* __restrict__ out) {
  __shared__ u16 sA[128 * 32];
  __shared__ u16 sB[128 * 32];
  const int tid = threadIdx.x, lane = tid & 63, wid = tid >> 6;
  const int wr = wid >> 1, wc = wid & 1;
  const int row0 = blockIdx.y * 128, col0 = blockIdx.x * 128;
  f4 acc[4][4] = {};

  for (int kt = 0; kt < DM / 32; ++kt) {
#pragma unroll
    for (int i = 0; i < 2; ++i) {
      int c = i * 4 + wid;
      int r = c * 16 + (lane >> 2);
      int s = (lane & 3) ^ ((r >> 1) & 3);
      gl_lds16(ab + (size_t)(row0 + r) * DM + kt * 32 + s * 8, &sA[c * 512 + lane * 8]);
      gl_lds16(wo + (size_t)(col0 + r) * DM + kt * 32 + s * 8, &sB[c * 512 + lane * 8]);
    }
    __syncthreads();
    bfx8 a[4], b[4];
#pragma unroll
    for (int t = 0; t < 4; ++t) {
      int ra = wr * 64 + t * 16 + (lane & 15);
      a[t] = *(const bfx8*)&sA[ra * 32 + (((lane >> 4) ^ ((ra >> 1) & 3)) * 8)];
      int rb = wc * 64 + t * 16 + (lane & 15);
      b[t] = *(const bfx8*)&sB[rb * 32 + (((lane >> 4) ^ ((rb >> 1) & 3)) * 8)];
    }
#pragma unroll
    for (int mt = 0; mt < 4; ++mt)
#pragma unroll
      for (int nt = 0; nt < 4; ++nt)
        acc[mt][nt] = __builtin_amdgcn_mfma_f32_16x16x32_bf16(a[mt], b[nt], acc[mt][nt], 0, 0, 0);
    __syncthreads();
  }

#pragma unroll
  for (int mt = 0; mt < 4; ++mt) {
#pragma unroll
    for (int nt = 0; nt < 4; ++nt) {
      int n = col0 + wc * 64 + nt * 16 + (lane & 15);
      float bv_ = bo[n];
#pragma unroll
      for (int r = 0; r < 4; ++r) {
        int mrow = row0 + wr * 64 + mt * 16 + (lane >> 4) * 4 + r;
        out[(size_t)mrow * DM + n] = acc[mt][nt][r] + bv_;
      }
    }
  }
}

// ---------------- flash attention, KV-split x2 ----------------
// grid 512: bid -> h (2 heads/XCD), half (KV 0..2047 / 2048..4095), qtile (256 rows).
// 8 waves x 32 q-rows; K/V LDS-staged via global_load_lds, double-buffered (R7 structure).
// Swapped QK^T in-register softmax (exp2 domain, T13 defer-max, packed-f32 trees).
// Writes UNNORMALIZED partial O^T (f32) + (m,l) per row; merge_kernel combines halves.

#define MFMA32(A, B, C) __builtin_amdgcn_mfma_f32_32x32x16_bf16(A, B, C, 0, 0, 0)

__device__ __forceinline__ void softmax_pack(
    f16f& s0, f16f& s1, float& m, float& l, f16f& o0, f16f& o1,
    bfx8& pa0, bfx8& pa1, bfx8& pa2, bfx8& pa3) {
  // packed-pair max tree over 32 scores
  f2 a0 = pkmax(mkf2(s0[0], s0[1]),   mkf2(s0[2], s0[3]));
  f2 a1 = pkmax(mkf2(s0[4], s0[5]),   mkf2(s0[6], s0[7]));
  f2 a2 = pkmax(mkf2(s0[8], s0[9]),   mkf2(s0[10], s0[11]));
  f2 a3 = pkmax(mkf2(s0[12], s0[13]), mkf2(s0[14], s0[15]));
  f2 b0 = pkmax(mkf2(s1[0], s1[1]),   mkf2(s1[2], s1[3]));
  f2 b1 = pkmax(mkf2(s1[4], s1[5]),   mkf2(s1[6], s1[7]));
  f2 b2 = pkmax(mkf2(s1[8], s1[9]),   mkf2(s1[10], s1[11]));
  f2 b3 = pkmax(mkf2(s1[12], s1[13]), mkf2(s1[14], s1[15]));
  a0 = pkmax(a0, a1); a2 = pkmax(a2, a3);
  b0 = pkmax(b0, b1); b2 = pkmax(b2, b3);
  a0 = pkmax(pkmax(a0, a2), pkmax(b0, b2));
  float tm = fmaxf(a0[0], a0[1]);
  tm = fmaxf(tm, __shfl_xor(tm, 32));
  // T13 defer-max: rescale only when some lane's tile-max exceeds m+8 (exp2 domain)
  if (!__all(tm <= m + 8.0f)) {
    float mn = fmaxf(m, tm);
    float fsc = __builtin_amdgcn_exp2f(m - mn);
    m = mn; l *= fsc;
#pragma unroll
    for (int r = 0; r < 16; ++r) { o0[r] *= fsc; o1[r] *= fsc; }
  }
  // exp2 with packed subtract
  f2 m2 = mkf2(m, m);
#pragma unroll
  for (int r = 0; r < 16; r += 2) {
    f2 t = mkf2(s0[r], s0[r + 1]) - m2;
    s0[r] = __builtin_amdgcn_exp2f(t[0]); s0[r + 1] = __builtin_amdgcn_exp2f(t[1]);
  }
#pragma unroll
  for (int r = 0; r < 16; r += 2) {
    f2 t = mkf2(s1[r], s1[r + 1]) - m2;
    s1[r] = __builtin_amdgcn_exp2f(t[0]); s1[r + 1] = __builtin_amdgcn_exp2f(t[1]);
  }
  // packed-pair sum tree
  f2 c0 = (mkf2(s0[0], s0[1]) + mkf2(s0[2], s0[3])) + (mkf2(s0[4], s0[5]) + mkf2(s0[6], s0[7]));
  f2 c1 = (mkf2(s0[8], s0[9]) + mkf2(s0[10], s0[11])) + (mkf2(s0[12], s0[13]) + mkf2(s0[14], s0[15]));
  f2 c2 = (mkf2(s1[0], s1[1]) + mkf2(s1[2], s1[3])) + (mkf2(s1[4], s1[5]) + mkf2(s1[6], s1[7]));
  f2 c3 = (mkf2(s1[8], s1[9]) + mkf2(s1[10], s1[11])) + (mkf2(s1[12], s1[13]) + mkf2(s1[14], s1[15]));
  c0 = (c0 + c1) + (c2 + c3);
  float ps = c0[0] + c0[1];
  ps += __shfl_xor(ps, 32);
  l += ps;
  // P(f32, S^T layout) -> bf16 PV fragments via cvt_pk + permlane32_swap (T12)
  uint32_t x0, x1, x2, x3;
#define PACK(SS, i0, PA)                                                     \
  x0 = cvtpk(SS[i0 + 0], SS[i0 + 1]); x1 = cvtpk(SS[i0 + 2], SS[i0 + 3]);    \
  x2 = cvtpk(SS[i0 + 4], SS[i0 + 5]); x3 = cvtpk(SS[i0 + 6], SS[i0 + 7]);    \
  pl32(x0, x2); pl32(x1, x3);                                                \
  { u32x4 t_; t_[0] = x0; t_[1] = x1; t_[2] = x2; t_[3] = x3;                \
    PA = __builtin_bit_cast(bfx8, t_); }
  PACK(s0, 0, pa0) PACK(s0, 8, pa1) PACK(s1, 0, pa2) PACK(s1, 8, pa3)
#undef PACK
}

__global__ __launch_bounds__(512, 4) void attn_kernel(
    const u16* __restrict__ qb, const u16* __restrict__ kb,
    const u16* __restrict__ vb, float* __restrict__ opart, float* __restrict__ mlb) {
  __shared__ u16 sK[2][64 * 64];
  __shared__ u16 sV[2][64 * 64];
  const int tid = threadIdx.x, lane = tid & 63, wid = tid >> 6;
  const int hi = lane >> 5, q32 = lane & 31;
  const int bid = blockIdx.x;
  // bid = [qtile:4][half:1][hbit:1][xcd:3]; 2 heads per XCD
  const int h = (bid & 7) * 2 + ((bid >> 3) & 1);
  const int half = (bid >> 4) & 1;
  const int qr0 = (bid >> 5) * 256 + wid * 32;
  const size_t hoff = (size_t)h * ((size_t)T_SEQ * DH);

  // Q fragments (B-operand): Q[q=lane&31][d = 16*ds + 8*hi + j]
  bfx8 qf0, qf1, qf2, qf3;
  {
    const u16* qp = qb + hoff + (size_t)(qr0 + q32) * DH + hi * 8;
    qf0 = *(const bfx8*)(qp);
    qf1 = *(const bfx8*)(qp + 16);
    qf2 = *(const bfx8*)(qp + 32);
    qf3 = *(const bfx8*)(qp + 48);
  }

  f16f o0 = {}, o1 = {};          // O^T accum: d rows 0-31 / 32-63, col q=lane&31
  float m = -INFINITY, l = 0.f;

  // staging: thread covers LDS row sr (0..63), 16B slot (tid&7); XOR-swizzled source
  const int sr = tid >> 3, ssl = (tid & 7) ^ (sr & 7);
  const u16* kg = kb + hoff + (size_t)(half * 2048 + sr) * DH + ssl * 8;
  const u16* vg = vb + hoff + (size_t)sr * T_SEQ + half * 2048 + ssl * 8;
  u16* dK0 = &sK[0][tid * 8]; u16* dK1 = &sK[1][tid * 8];
  u16* dV0 = &sV[0][tid * 8]; u16* dV1 = &sV[1][tid * 8];

  gl_lds16(kg, dK0);
  gl_lds16(vg, dV0);
  __syncthreads();

  const int NTH = 2048 / 64;      // 32 tiles per half
  const int x0s = (q32 & 7) * 8;  // swizzle term (rows r and r+32 share r&7)
  for (int kt = 0; kt < NTH; ++kt) {
    const u16* Kc = (kt & 1) ? sK[1] : sK[0];
    const u16* Vc = (kt & 1) ? sV[1] : sV[0];
    if (kt + 1 < NTH) {  // prefetch next tile into other buffer
      gl_lds16(kg + (size_t)(kt + 1) * 64 * DH, (kt & 1) ? dK0 : dK1);
      gl_lds16(vg + (size_t)(kt + 1) * 64,     (kt & 1) ? dV0 : dV1);
    }

    // S^T = K Q^T : s0 = k rows 0-31, s1 = k rows 32-63 (col = q = lane&31)
    f16f s0 = {}, s1 = {};
    {
      const int c0 = q32 * 64, c1 = (32 + q32) * 64;
      __builtin_amdgcn_s_setprio(1);
#define QKSTEP(ds, QF)                                                              \
      {                                                                             \
        bfx8 kf0 = *(const bfx8*)&Kc[c0 + (((2 * ds + hi) * 8) ^ x0s)];             \
        s0 = MFMA32(kf0, QF, s0);                                                   \
        bfx8 kf1 = *(const bfx8*)&Kc[c1 + (((2 * ds + hi) * 8) ^ x0s)];             \
        s1 = MFMA32(kf1, QF, s1);                                                   \
      }
      QKSTEP(0, qf0) QKSTEP(1, qf1) QKSTEP(2, qf2) QKSTEP(3, qf3)
#undef QKSTEP
      __builtin_amdgcn_s_setprio(0);
    }

    bfx8 pa0, pa1, pa2, pa3;
    softmax_pack(s0, s1, m, l, o0, o1, pa0, pa1, pa2, pa3);

    // O^T += V^T P^T : A = V^T rows (d), B = P fragments
    {
      const int d0 = q32 * 64, d1 = (32 + q32) * 64;
      __builtin_amdgcn_s_setprio(1);
#define PVSTEP(ks, PA)                                                              \
      {                                                                             \
        bfx8 vf0 = *(const bfx8*)&Vc[d0 + (((2 * ks + hi) * 8) ^ x0s)];             \
        o0 = MFMA32(vf0, PA, o0);                                                   \
        bfx8 vf1 = *(const bfx8*)&Vc[d1 + (((2 * ks + hi) * 8) ^ x0s)];             \
        o1 = MFMA32(vf1, PA, o1);                                                   \
      }
      PVSTEP(0, pa0) PVSTEP(1, pa1) PVSTEP(2, pa2) PVSTEP(3, pa3)
#undef PVSTEP
      __builtin_amdgcn_s_setprio(0);
    }
    __syncthreads();  // staged tile kt+1 ready; all waves done reading tile kt
  }

  // epilogue: write UNNORMALIZED partial O^T (f32) + (m,l)
  const int R = h * T_SEQ + qr0 + q32;
  float* op = opart + (size_t)half * (65536ull * 64) + (size_t)R * 64;
#pragma unroll
  for (int g = 0; g < 4; ++g) {
    float4 t0; t0.x = o0[4 * g]; t0.y = o0[4 * g + 1]; t0.z = o0[4 * g + 2]; t0.w = o0[4 * g + 3];
    *(float4*)(op + 8 * g + 4 * hi) = t0;
    float4 t1; t1.x = o1[4 * g]; t1.y = o1[4 * g + 1]; t1.z = o1[4 * g + 2]; t1.w = o1[4 * g + 3];
    *(float4*)(op + 32 + 8 * g + 4 * hi) = t1;
  }
  if (hi == 0) {
    float2 t; t.x = m; t.y = l;
    *(float2*)(mlb + (size_t)(half * 65536 + R) * 2) = t;
  }
}

// ---------------- merge the two KV halves ----------------
__global__ __launch_bounds__(256) void merge_kernel(
    const float* __restrict__ op, const float* __restrict__ mlb,
    u16* __restrict__ ao) {
  const int tid = threadIdx.x;
  const int lane = tid & 63;            // d
  const int rsub = tid >> 6;            // 0..3
  const int R = blockIdx.x * 4 + rsub;  // h*4096 + qrow
  const int h = R >> 12, qrow = R & 4095;
  const float m0 = mlb[(size_t)R * 2],             l0 = mlb[(size_t)R * 2 + 1];
  const float m1 = mlb[(size_t)(65536 + R) * 2],   l1 = mlb[(size_t)(65536 + R) * 2 + 1];
  float mm = fmaxf(m0, m1);
  float f0 = __builtin_amdgcn_exp2f(m0 - mm);
  float f1 = __builtin_amdgcn_exp2f(m1 - mm);
  float inv = 1.0f / (f0 * l0 + f1 * l1);
  float v0 = op[(size_t)R * 64 + lane];
  float v1 = op[65536ull * 64 + (size_t)R * 64 + lane];
  ao[(size_t)qrow * DM + h * DH + lane] = f2bf((f0 * v0 + f1 * v1) * inv);
}

extern "C" void kernel_launch(void* const* d_in, const int* in_sizes, int n_in,
                              void* d_out, int out_size, void* d_ws, size_t ws_size,
                              hipStream_t stream) {
  const float* x  = (const float*)d_in[0];
  const float* Wq = (const float*)d_in[1];
  const float* bq = (const float*)d_in[2];
  const float* Wk = (const float*)d_in[3];
  const float* bk = (const float*)d_in[4];
  const float* Wv = (const float*)d_in[5];
  const float* bv = (const float*)d_in[6];
  const float* Wo = (const float*)d_in[7];
  const float* bo = (const float*)d_in[8];
  float* out = (float*)d_out;

  u16* ws  = (u16*)d_ws;
  u16* xb  = ws;                                // [4096][1024]
  u16* wqb = xb + (size_t)T_SEQ * DM;           // [1024][1024] each
  u16* wkb = wqb + (size_t)DM * DM;
  u16* wvb = wkb + (size_t)DM * DM;
  u16* wob = wvb + (size_t)DM * DM;
  u16* qbb = wob + (size_t)DM * DM;             // [16][4096][64] (q, pre-scaled)
  u16* kbb = qbb + (size_t)T_SEQ * DM;          // [16][4096][64]
  u16* vbb = kbb + (size_t)T_SEQ * DM;          // [16][64][4096] (transposed)
  u16* abb = vbb + (size_t)T_SEQ * DM;          // [4096][1024] attn merged (bf16)
  float* opart = (float*)(abb + (size_t)T_SEQ * DM);  // [2][16*4096][64] f32 = 32MB @48MB
  float* mlb   = opart + 2ull * 65536 * 64;           // [2][16*4096][2] f32 = 1MB

  cvt_kernel<<<(T_SEQ * DM / 8) / 256, 256, 0, stream>>>(x, xb, T_SEQ * DM / 8);
  cvt4_kernel<<<dim3((DM * DM / 8) / 256, 4), 256, 0, stream>>>(
      Wq, Wk, Wv, Wo, wqb, wkb, wvb, wob);

  gemm_qkv<<<dim3(DM / 128, T_SEQ / 128, 3), 256, 0, stream>>>(
      xb, wqb, wkb, wvb, bq, bk, bv, qbb, kbb, vbb);

  attn_kernel<<<512, 512, 0, stream>>>(qbb, kbb, vbb, opart, mlb);
  merge_kernel<<<65536 / 4, 256, 0, stream>>>(opart, mlb, abb);

  gemm_out<<<dim3(DM / 128, T_SEQ / 128), 256, 0, stream>>>(abb, wob, bo, out);
}